// Round 3
// baseline (1740.992 us; speedup 1.0000x reference)
//
#include <hip/hip_runtime.h>

typedef __attribute__((ext_vector_type(8))) short short8v;   // 8 bf16 (4 VGPRs)
typedef __attribute__((ext_vector_type(4))) float f32x4;     // MFMA accumulator

#define N_ROWS 8192
#define KSPLIT 768          // 3 x 256 (hi|lo|hi concatenation)
#define SEP 64
#define TLO (-50.0f)
#define THI (50.0f)
#define LIST_CAP (1u << 20)

// ---------- helpers ----------
__device__ inline unsigned f2ord(float x){
  unsigned u = __float_as_uint(x);
  return (u & 0x80000000u) ? ~u : (u | 0x80000000u);   // monotone f32 -> u32
}
__device__ inline float ord2f(unsigned u){
  unsigned b = (u & 0x80000000u) ? (u & 0x7fffffffu) : ~u;
  return __uint_as_float(b);
}
__device__ inline unsigned short bf16rn(float x){
  unsigned b = __float_as_uint(x);
  unsigned r = (b + 0x7fffu + ((b >> 16) & 1u)) >> 16;  // round-to-nearest-even
  return (unsigned short)r;
}
__device__ inline void gload16(const void* g, void* l){
  __builtin_amdgcn_global_load_lds((const __attribute__((address_space(1))) void*)g,
                                   (__attribute__((address_space(3))) void*)l, 16, 0, 0);
}
__device__ inline int bin_of(float v, float mnv, float interval){
  float r = (v - mnv) / interval;                       // true division, like ref
  int b = (int)floorf(r);
  return b < 0 ? 0 : (b > 63 ? 63 : b);
}

// ---------- K0: split f32 -> bf16 hi/lo, K-concatenated ----------
// cur2  = [hi | lo | hi]  (8192 x 768 bf16)
// prev2 = [hi | hi | lo]
// => sum over K=768 gives hi*hi + lo*hi + hi*lo (drops only lo*lo ~1e-4)
__global__ void split_kernel(const float* __restrict__ cur, const float* __restrict__ prev,
                             unsigned short* __restrict__ cur2, unsigned short* __restrict__ prev2){
  int g = blockIdx.x * blockDim.x + threadIdx.x;         // 0 .. 2*524288-1
  int isB = (g >= (N_ROWS * 256 / 4)) ? 1 : 0;
  int t = g - isB * (N_ROWS * 256 / 4);
  const float4 v = ((const float4*)(isB ? prev : cur))[t];
  int row = t >> 6;                                      // 64 float4 per 256-col row
  int col = (t & 63) << 2;
  float xs[4] = {v.x, v.y, v.z, v.w};
  unsigned short h[4], l[4];
  #pragma unroll
  for (int j = 0; j < 4; ++j){
    unsigned short hb = bf16rn(xs[j]);
    float hf = __uint_as_float(((unsigned)hb) << 16);
    h[j] = hb;
    l[j] = bf16rn(xs[j] - hf);                           // residual capture
  }
  unsigned short* dst = isB ? prev2 : cur2;
  size_t base = (size_t)row * KSPLIT + col;
  uint2 hw, lw;
  hw.x = (unsigned)h[0] | ((unsigned)h[1] << 16); hw.y = (unsigned)h[2] | ((unsigned)h[3] << 16);
  lw.x = (unsigned)l[0] | ((unsigned)l[1] << 16); lw.y = (unsigned)l[2] | ((unsigned)l[3] << 16);
  *(uint2*)(dst + base) = hw;
  if (!isB){
    *(uint2*)(dst + base + 256) = lw;
    *(uint2*)(dst + base + 512) = hw;
  } else {
    *(uint2*)(dst + base + 256) = hw;
    *(uint2*)(dst + base + 512) = lw;
  }
}

// ---------- GEMM: 128x128 tile, 4 waves (2x2), 16x16x32 bf16 MFMA ----------
// EPI 0: min/max only
// EPI 2: exact 64-bin histogram (fallback; early-exits when *flag == 0)
// EPI 3: min/max + tail-value list (|v| > 50 -> compacted global list)
template<int EPI>
__global__ __launch_bounds__(256) void gemm_kernel(const unsigned short* __restrict__ A2,
                                                   const unsigned short* __restrict__ B2,
                                                   unsigned* __restrict__ mm,
                                                   unsigned* __restrict__ hist,
                                                   float* __restrict__ list,
                                                   unsigned* __restrict__ lcnt,
                                                   const unsigned* __restrict__ flag){
  if (EPI == 2){
    if (flag[0] == 0u) return;                           // main path succeeded: no-op
  }
  __shared__ unsigned short As[128 * 32];
  __shared__ unsigned short Bs[128 * 32];
  __shared__ float red[8];
  __shared__ unsigned lh[SEP];

  const int tid  = threadIdx.x;
  const int lane = tid & 63;
  const int wave = tid >> 6;
  const int bm = blockIdx.x >> 6;
  const int bn = blockIdx.x & 63;
  const int wr = wave >> 1, wc = wave & 1;

  const size_t aBase = (size_t)bm * 128 * KSPLIT;
  const size_t bBase = (size_t)bn * 128 * KSPLIT;
  const int id0 = tid, id1 = tid + 256;                  // 512 x 16B chunks per tile
  const size_t aOff0 = aBase + (size_t)(id0 >> 2) * KSPLIT + (id0 & 3) * 8;
  const size_t aOff1 = aBase + (size_t)(id1 >> 2) * KSPLIT + (id1 & 3) * 8;
  const size_t bOff0 = bBase + (size_t)(id0 >> 2) * KSPLIT + (id0 & 3) * 8;
  const size_t bOff1 = bBase + (size_t)(id1 >> 2) * KSPLIT + (id1 & 3) * 8;

  f32x4 acc[4][4];
  #pragma unroll
  for (int m = 0; m < 4; ++m)
    #pragma unroll
    for (int n = 0; n < 4; ++n)
      acc[m][n] = (f32x4){0.f, 0.f, 0.f, 0.f};

  const int rsel = lane & 15;
  const int ksel = (lane >> 4) * 8;

  for (int ks = 0; ks < KSPLIT / 32; ++ks){
    const int k0 = ks * 32;
    gload16(A2 + aOff0 + k0, As + id0 * 8);
    gload16(A2 + aOff1 + k0, As + id1 * 8);
    gload16(B2 + bOff0 + k0, Bs + id0 * 8);
    gload16(B2 + bOff1 + k0, Bs + id1 * 8);
    __syncthreads();
    short8v a[4], b[4];
    #pragma unroll
    for (int m = 0; m < 4; ++m)
      a[m] = *(const short8v*)(As + (wr * 64 + m * 16 + rsel) * 32 + ksel);
    #pragma unroll
    for (int n = 0; n < 4; ++n)
      b[n] = *(const short8v*)(Bs + (wc * 64 + n * 16 + rsel) * 32 + ksel);
    #pragma unroll
    for (int m = 0; m < 4; ++m)
      #pragma unroll
      for (int n = 0; n < 4; ++n)
        acc[m][n] = __builtin_amdgcn_mfma_f32_16x16x32_bf16(a[m], b[n], acc[m][n], 0, 0, 0);
    __syncthreads();
  }

  if (EPI == 0 || EPI == 3){
    float mn = 3.4e38f, mx = -3.4e38f;
    #pragma unroll
    for (int m = 0; m < 4; ++m)
      #pragma unroll
      for (int n = 0; n < 4; ++n)
        #pragma unroll
        for (int q = 0; q < 4; ++q){
          float v = acc[m][n][q];
          mn = fminf(mn, v); mx = fmaxf(mx, v);
          if (EPI == 3 && (v < TLO || v > THI)){
            unsigned idx = atomicAdd(lcnt, 1u);
            if (idx < LIST_CAP) list[idx] = v;
          }
        }
    #pragma unroll
    for (int off = 32; off; off >>= 1){
      mn = fminf(mn, __shfl_xor(mn, off));
      mx = fmaxf(mx, __shfl_xor(mx, off));
    }
    if (lane == 0){ red[wave] = mn; red[4 + wave] = mx; }
    __syncthreads();
    if (tid == 0){
      mn = fminf(fminf(red[0], red[1]), fminf(red[2], red[3]));
      mx = fmaxf(fmaxf(red[4], red[5]), fmaxf(red[6], red[7]));
      atomicMin(mm + 0, f2ord(mn));
      atomicMax(mm + 1, f2ord(mx));
    }
  }
  if (EPI == 2){
    if (tid < SEP) lh[tid] = 0u;
    __syncthreads();
    const float mnv = ord2f(mm[0]);
    const float mxv = ord2f(mm[1]);
    const float interval = (mxv - mnv) / 64.0f;
    #pragma unroll
    for (int m = 0; m < 4; ++m)
      #pragma unroll
      for (int n = 0; n < 4; ++n)
        #pragma unroll
        for (int q = 0; q < 4; ++q)
          atomicAdd(&lh[bin_of(acc[m][n][q], mnv, interval)], 1u);
    __syncthreads();
    if (tid < SEP){ unsigned c = lh[tid]; if (c) atomicAdd(hist + tid, c); }
  }
}

// ---------- finalize from tail list (1 block). Sets flag: 0 = done, 1 = need fallback ----
__global__ void finalize1_kernel(const unsigned* __restrict__ mm,
                                 const unsigned* __restrict__ lcnt,
                                 const float* __restrict__ list,
                                 const float* __restrict__ W,
                                 unsigned* __restrict__ flag,
                                 float* __restrict__ out){
  __shared__ unsigned h[SEP];
  const int tid = threadIdx.x;
  if (tid < SEP) h[tid] = 0u;
  __syncthreads();
  const float mnv = ord2f(mm[0]);
  const float mxv = ord2f(mm[1]);
  const float interval = (mxv - mnv) / 64.0f;
  const unsigned cnt = lcnt[0];
  const unsigned n = cnt > LIST_CAP ? LIST_CAP : cnt;
  for (unsigned i = tid; i < n; i += blockDim.x)
    atomicAdd(&h[bin_of(list[i], mnv, interval)], 1u);
  __syncthreads();
  if (tid == 0){
    // binning is monotone in v (f32 sub/div/floor preserve order), so:
    //  - every v with bin(v) <  bin(TLO) satisfies v < TLO  -> fully in list -> exact
    //  - every v with bin(v) >  bin(THI) satisfies v > THI  -> fully in list -> exact
    const int bLO = bin_of(TLO, mnv, interval);
    const int bHI = bin_of(THI, mnv, interval);
    bool ok = (cnt <= LIST_CAP) && (bLO >= 3) && (bHI <= 60) && (bLO < bHI)
              && (h[bLO - 1] >= 30u) && (h[bHI + 1] >= 30u);
    if (ok){
      float p = 0.f;
      for (int j = 0; j < SEP; ++j){
        float beta;
        if (j < bLO || j > bHI) beta = 1.f / (1.f + expf(-(float)h[j]));
        else beta = 1.0f;                                // count >= 30 -> sigmoid == 1.0f
        p += beta * W[j];
      }
      out[0] = 1.f / (1.f + expf(-p));
      flag[0] = 0u;
    } else {
      flag[0] = 1u;                                      // run exact fallback pass
    }
  }
}

// ---------- fallback finalize: out = sigmoid( sum_j sigmoid(count_j) * W_j ) ----------
__global__ void fin_kernel(const unsigned* __restrict__ hist, const float* __restrict__ W,
                           const unsigned* __restrict__ flag, float* __restrict__ out){
  if (flag[0] == 0u) return;                             // finalize1 already wrote out
  int j = threadIdx.x;                                   // 64 threads = 1 wave
  float beta = 1.f / (1.f + expf(-(float)hist[j]));
  float p = beta * W[j];
  #pragma unroll
  for (int off = 32; off; off >>= 1) p += __shfl_down(p, off);
  if (j == 0) out[0] = 1.f / (1.f + expf(-p));
}

extern "C" void kernel_launch(void* const* d_in, const int* in_sizes, int n_in,
                              void* d_out, int out_size, void* d_ws, size_t ws_size,
                              hipStream_t stream){
  const float* cur  = (const float*)d_in[0];
  const float* prev = (const float*)d_in[1];
  const float* W    = (const float*)d_in[2];
  float* out = (float*)d_out;
  char* ws = (char*)d_ws;

  // ws layout
  unsigned short* cur2  = (unsigned short*)ws;                 // 12,582,912 B
  unsigned short* prev2 = (unsigned short*)(ws + 12582912);    // 12,582,912 B
  unsigned* mm   = (unsigned*)(ws + 25165824);                 // [min,max] ordered-u32
  unsigned* flag = (unsigned*)(ws + 25165832);
  unsigned* lcnt = (unsigned*)(ws + 25165836);
  unsigned* hist = (unsigned*)(ws + 25165840);                 // 64 x u32 (ends 25166096)
  float*    list = (float*)(ws + 25166336);                    // 4 MiB tail list
  const size_t NEED_NEW = 25166336 + (size_t)LIST_CAP * 4;     // ~29.4 MB

  // init: min <- +inf-order, {max, flag, lcnt, hist} <- 0, then flag <- 1
  hipMemsetAsync(mm, 0xFF, 4, stream);
  hipMemsetAsync((char*)mm + 4, 0, 4 + 4 + 4 + 256, stream);
  hipMemsetAsync(flag, 1, 1, stream);                          // flag = 1 (fallback default)

  split_kernel<<<4096, 256, 0, stream>>>(cur, prev, cur2, prev2);

  if (ws_size >= NEED_NEW){
    // single-GEMM path: minmax + tail list, then analytic finalize; guarded fallback
    gemm_kernel<3><<<4096, 256, 0, stream>>>(cur2, prev2, mm, hist, list, lcnt, flag);
    finalize1_kernel<<<1, 256, 0, stream>>>(mm, lcnt, list, W, flag, out);
    gemm_kernel<2><<<4096, 256, 0, stream>>>(cur2, prev2, mm, hist, list, lcnt, flag);
    fin_kernel<<<1, 64, 0, stream>>>(hist, W, flag, out);
  } else {
    // verified 2-pass path (flag stays 1 -> EPI2 + fin run fully)
    gemm_kernel<0><<<4096, 256, 0, stream>>>(cur2, prev2, mm, hist, list, lcnt, flag);
    gemm_kernel<2><<<4096, 256, 0, stream>>>(cur2, prev2, mm, hist, list, lcnt, flag);
    fin_kernel<<<1, 64, 0, stream>>>(hist, W, flag, out);
  }
}

// Round 4
// 445.658 us; speedup vs baseline: 3.9066x; 3.9066x over previous
//
#include <hip/hip_runtime.h>

typedef __attribute__((ext_vector_type(8))) short short8v;   // 8 bf16 (4 VGPRs)
typedef __attribute__((ext_vector_type(4))) float f32x4;     // MFMA accumulator

#define N_ROWS 8192
#define KSPLIT 768          // 3 x 256 (hi|lo|hi concatenation)
#define SEP 64
#define TLO (-50.0f)
#define THI (50.0f)
#define LIST_CAP (1u << 20)
#define TAIL_CAP 1024u      // per-block LDS tail buffer (expected ~29 tails/block)

// ---------- helpers ----------
__device__ inline unsigned f2ord(float x){
  unsigned u = __float_as_uint(x);
  return (u & 0x80000000u) ? ~u : (u | 0x80000000u);   // monotone f32 -> u32
}
__device__ inline float ord2f(unsigned u){
  unsigned b = (u & 0x80000000u) ? (u & 0x7fffffffu) : ~u;
  return __uint_as_float(b);
}
__device__ inline unsigned short bf16rn(float x){
  unsigned b = __float_as_uint(x);
  unsigned r = (b + 0x7fffu + ((b >> 16) & 1u)) >> 16;  // round-to-nearest-even
  return (unsigned short)r;
}
__device__ inline void gload16(const void* g, void* l){
  __builtin_amdgcn_global_load_lds((const __attribute__((address_space(1))) void*)g,
                                   (__attribute__((address_space(3))) void*)l, 16, 0, 0);
}
__device__ inline int bin_of(float v, float mnv, float interval){
  float r = (v - mnv) / interval;                       // true division, like ref
  int b = (int)floorf(r);
  return b < 0 ? 0 : (b > 63 ? 63 : b);
}

// ---------- K0: split f32 -> bf16 hi/lo, K-concatenated ----------
// cur2  = [hi | lo | hi]  (8192 x 768 bf16)
// prev2 = [hi | hi | lo]
// => sum over K=768 gives hi*hi + lo*hi + hi*lo (drops only lo*lo ~1e-4)
__global__ void split_kernel(const float* __restrict__ cur, const float* __restrict__ prev,
                             unsigned short* __restrict__ cur2, unsigned short* __restrict__ prev2){
  int g = blockIdx.x * blockDim.x + threadIdx.x;         // 0 .. 2*524288-1
  int isB = (g >= (N_ROWS * 256 / 4)) ? 1 : 0;
  int t = g - isB * (N_ROWS * 256 / 4);
  const float4 v = ((const float4*)(isB ? prev : cur))[t];
  int row = t >> 6;                                      // 64 float4 per 256-col row
  int col = (t & 63) << 2;
  float xs[4] = {v.x, v.y, v.z, v.w};
  unsigned short h[4], l[4];
  #pragma unroll
  for (int j = 0; j < 4; ++j){
    unsigned short hb = bf16rn(xs[j]);
    float hf = __uint_as_float(((unsigned)hb) << 16);
    h[j] = hb;
    l[j] = bf16rn(xs[j] - hf);                           // residual capture
  }
  unsigned short* dst = isB ? prev2 : cur2;
  size_t base = (size_t)row * KSPLIT + col;
  uint2 hw, lw;
  hw.x = (unsigned)h[0] | ((unsigned)h[1] << 16); hw.y = (unsigned)h[2] | ((unsigned)h[3] << 16);
  lw.x = (unsigned)l[0] | ((unsigned)l[1] << 16); lw.y = (unsigned)l[2] | ((unsigned)l[3] << 16);
  *(uint2*)(dst + base) = hw;
  if (!isB){
    *(uint2*)(dst + base + 256) = lw;
    *(uint2*)(dst + base + 512) = hw;
  } else {
    *(uint2*)(dst + base + 256) = hw;
    *(uint2*)(dst + base + 512) = lw;
  }
}

// ---------- GEMM: 128x128 tile, 4 waves (2x2), 16x16x32 bf16 MFMA ----------
// EPI 0: min/max only
// EPI 2: exact 64-bin histogram (fallback; early-exits when *flag == 0)
// EPI 3: min/max + tail list, per-block aggregated (ONE lcnt atomic per block)
template<int EPI>
__global__ __launch_bounds__(256) void gemm_kernel(const unsigned short* __restrict__ A2,
                                                   const unsigned short* __restrict__ B2,
                                                   unsigned* __restrict__ mm,
                                                   unsigned* __restrict__ hist,
                                                   float* __restrict__ list,
                                                   unsigned* __restrict__ lcnt,
                                                   const unsigned* __restrict__ flag){
  if (EPI == 2){
    if (flag[0] == 0u) return;                           // main path succeeded: no-op
  }
  __shared__ unsigned short As[128 * 32];
  __shared__ unsigned short Bs[128 * 32];
  __shared__ float red[8];
  __shared__ unsigned lh[SEP];
  __shared__ float lbuf[TAIL_CAP];
  __shared__ unsigned lcount, base_s;

  const int tid  = threadIdx.x;
  const int lane = tid & 63;
  const int wave = tid >> 6;
  const int bm = blockIdx.x >> 6;
  const int bn = blockIdx.x & 63;
  const int wr = wave >> 1, wc = wave & 1;

  if (EPI == 3 && tid == 0) lcount = 0u;                 // visible after 1st K-loop barrier

  const size_t aBase = (size_t)bm * 128 * KSPLIT;
  const size_t bBase = (size_t)bn * 128 * KSPLIT;
  const int id0 = tid, id1 = tid + 256;                  // 512 x 16B chunks per tile
  const size_t aOff0 = aBase + (size_t)(id0 >> 2) * KSPLIT + (id0 & 3) * 8;
  const size_t aOff1 = aBase + (size_t)(id1 >> 2) * KSPLIT + (id1 & 3) * 8;
  const size_t bOff0 = bBase + (size_t)(id0 >> 2) * KSPLIT + (id0 & 3) * 8;
  const size_t bOff1 = bBase + (size_t)(id1 >> 2) * KSPLIT + (id1 & 3) * 8;

  f32x4 acc[4][4];
  #pragma unroll
  for (int m = 0; m < 4; ++m)
    #pragma unroll
    for (int n = 0; n < 4; ++n)
      acc[m][n] = (f32x4){0.f, 0.f, 0.f, 0.f};

  const int rsel = lane & 15;
  const int ksel = (lane >> 4) * 8;

  for (int ks = 0; ks < KSPLIT / 32; ++ks){
    const int k0 = ks * 32;
    gload16(A2 + aOff0 + k0, As + id0 * 8);
    gload16(A2 + aOff1 + k0, As + id1 * 8);
    gload16(B2 + bOff0 + k0, Bs + id0 * 8);
    gload16(B2 + bOff1 + k0, Bs + id1 * 8);
    __syncthreads();
    short8v a[4], b[4];
    #pragma unroll
    for (int m = 0; m < 4; ++m)
      a[m] = *(const short8v*)(As + (wr * 64 + m * 16 + rsel) * 32 + ksel);
    #pragma unroll
    for (int n = 0; n < 4; ++n)
      b[n] = *(const short8v*)(Bs + (wc * 64 + n * 16 + rsel) * 32 + ksel);
    #pragma unroll
    for (int m = 0; m < 4; ++m)
      #pragma unroll
      for (int n = 0; n < 4; ++n)
        acc[m][n] = __builtin_amdgcn_mfma_f32_16x16x32_bf16(a[m], b[n], acc[m][n], 0, 0, 0);
    __syncthreads();
  }

  if (EPI == 0 || EPI == 3){
    float mn = 3.4e38f, mx = -3.4e38f;
    #pragma unroll
    for (int m = 0; m < 4; ++m)
      #pragma unroll
      for (int n = 0; n < 4; ++n)
        #pragma unroll
        for (int q = 0; q < 4; ++q){
          float v = acc[m][n][q];
          mn = fminf(mn, v); mx = fmaxf(mx, v);
          if (EPI == 3 && fabsf(v) > THI){               // tail: spill to LDS (rare)
            unsigned li = atomicAdd(&lcount, 1u);
            if (li < TAIL_CAP) lbuf[li] = v;
            else {                                       // LDS overflow: direct global (rare^2)
              unsigned gi = atomicAdd(lcnt, 1u);
              if (gi < LIST_CAP) list[gi] = v;
            }
          }
        }
    #pragma unroll
    for (int off = 32; off; off >>= 1){
      mn = fminf(mn, __shfl_xor(mn, off));
      mx = fmaxf(mx, __shfl_xor(mx, off));
    }
    if (lane == 0){ red[wave] = mn; red[4 + wave] = mx; }
    __syncthreads();                                     // red + lcount final
    if (tid == 0){
      mn = fminf(fminf(red[0], red[1]), fminf(red[2], red[3]));
      mx = fmaxf(fmaxf(red[4], red[5]), fmaxf(red[6], red[7]));
      atomicMin(mm + 0, f2ord(mn));
      atomicMax(mm + 1, f2ord(mx));
      if (EPI == 3){
        unsigned c = lcount;
        unsigned cc = c > TAIL_CAP ? TAIL_CAP : c;
        base_s = cc ? atomicAdd(lcnt, cc) : 0u;          // ONE global atomic per block
        lcount = cc;
      }
    }
    __syncthreads();
    if (EPI == 3){
      const unsigned cc = lcount, base = base_s;
      for (unsigned i = tid; i < cc; i += 256u){
        unsigned gi = base + i;
        if (gi < LIST_CAP) list[gi] = lbuf[i];
      }
    }
  }
  if (EPI == 2){
    if (tid < SEP) lh[tid] = 0u;
    __syncthreads();
    const float mnv = ord2f(mm[0]);
    const float mxv = ord2f(mm[1]);
    const float interval = (mxv - mnv) / 64.0f;
    #pragma unroll
    for (int m = 0; m < 4; ++m)
      #pragma unroll
      for (int n = 0; n < 4; ++n)
        #pragma unroll
        for (int q = 0; q < 4; ++q)
          atomicAdd(&lh[bin_of(acc[m][n][q], mnv, interval)], 1u);
    __syncthreads();
    if (tid < SEP){ unsigned c = lh[tid]; if (c) atomicAdd(hist + tid, c); }
  }
}

// ---------- finalize from tail list (1 block). Sets flag: 0 = done, 1 = need fallback ----
__global__ void finalize1_kernel(const unsigned* __restrict__ mm,
                                 const unsigned* __restrict__ lcnt,
                                 const float* __restrict__ list,
                                 const float* __restrict__ W,
                                 unsigned* __restrict__ flag,
                                 float* __restrict__ out){
  __shared__ unsigned h[SEP];
  const int tid = threadIdx.x;
  if (tid < SEP) h[tid] = 0u;
  __syncthreads();
  const float mnv = ord2f(mm[0]);
  const float mxv = ord2f(mm[1]);
  const float interval = (mxv - mnv) / 64.0f;
  const unsigned cnt = lcnt[0];
  const unsigned n = cnt > LIST_CAP ? LIST_CAP : cnt;
  for (unsigned i = tid; i < n; i += blockDim.x)
    atomicAdd(&h[bin_of(list[i], mnv, interval)], 1u);
  __syncthreads();
  if (tid == 0){
    // binning is monotone in v (f32 sub/div/floor preserve order), so:
    //  - every v with bin(v) <  bin(TLO) satisfies v < TLO  -> fully in list -> exact
    //  - every v with bin(v) >  bin(THI) satisfies v > THI  -> fully in list -> exact
    const int bLO = bin_of(TLO, mnv, interval);
    const int bHI = bin_of(THI, mnv, interval);
    bool ok = (cnt <= LIST_CAP) && (bLO >= 3) && (bHI <= 60) && (bLO < bHI)
              && (h[bLO - 1] >= 30u) && (h[bHI + 1] >= 30u);
    if (ok){
      float p = 0.f;
      for (int j = 0; j < SEP; ++j){
        float beta;
        if (j < bLO || j > bHI) beta = 1.f / (1.f + expf(-(float)h[j]));
        else beta = 1.0f;                                // count >= 30 -> sigmoid == 1.0f
        p += beta * W[j];
      }
      out[0] = 1.f / (1.f + expf(-p));
      flag[0] = 0u;
    } else {
      flag[0] = 1u;                                      // run exact fallback pass
    }
  }
}

// ---------- fallback finalize: out = sigmoid( sum_j sigmoid(count_j) * W_j ) ----------
__global__ void fin_kernel(const unsigned* __restrict__ hist, const float* __restrict__ W,
                           const unsigned* __restrict__ flag, float* __restrict__ out){
  if (flag[0] == 0u) return;                             // finalize1 already wrote out
  int j = threadIdx.x;                                   // 64 threads = 1 wave
  float beta = 1.f / (1.f + expf(-(float)hist[j]));
  float p = beta * W[j];
  #pragma unroll
  for (int off = 32; off; off >>= 1) p += __shfl_down(p, off);
  if (j == 0) out[0] = 1.f / (1.f + expf(-p));
}

extern "C" void kernel_launch(void* const* d_in, const int* in_sizes, int n_in,
                              void* d_out, int out_size, void* d_ws, size_t ws_size,
                              hipStream_t stream){
  const float* cur  = (const float*)d_in[0];
  const float* prev = (const float*)d_in[1];
  const float* W    = (const float*)d_in[2];
  float* out = (float*)d_out;
  char* ws = (char*)d_ws;

  // ws layout
  unsigned short* cur2  = (unsigned short*)ws;                 // 12,582,912 B
  unsigned short* prev2 = (unsigned short*)(ws + 12582912);    // 12,582,912 B
  unsigned* mm   = (unsigned*)(ws + 25165824);                 // [min,max] ordered-u32
  unsigned* flag = (unsigned*)(ws + 25165832);
  unsigned* lcnt = (unsigned*)(ws + 25165836);
  unsigned* hist = (unsigned*)(ws + 25165840);                 // 64 x u32 (ends 25166096)
  float*    list = (float*)(ws + 25166336);                    // 4 MiB tail list
  const size_t NEED_NEW = 25166336 + (size_t)LIST_CAP * 4;     // ~29.4 MB

  // init: min <- +inf-order, {max, flag, lcnt, hist} <- 0, then flag <- 1
  hipMemsetAsync(mm, 0xFF, 4, stream);
  hipMemsetAsync((char*)mm + 4, 0, 4 + 4 + 4 + 256, stream);
  hipMemsetAsync(flag, 1, 1, stream);                          // flag = 1 (fallback default)

  split_kernel<<<4096, 256, 0, stream>>>(cur, prev, cur2, prev2);

  if (ws_size >= NEED_NEW){
    // single-GEMM path: minmax + tail list, then analytic finalize; guarded fallback
    gemm_kernel<3><<<4096, 256, 0, stream>>>(cur2, prev2, mm, hist, list, lcnt, flag);
    finalize1_kernel<<<1, 256, 0, stream>>>(mm, lcnt, list, W, flag, out);
    gemm_kernel<2><<<4096, 256, 0, stream>>>(cur2, prev2, mm, hist, list, lcnt, flag);
    fin_kernel<<<1, 64, 0, stream>>>(hist, W, flag, out);
  } else {
    // verified 2-pass path (flag stays 1 -> EPI2 + fin run fully)
    gemm_kernel<0><<<4096, 256, 0, stream>>>(cur2, prev2, mm, hist, list, lcnt, flag);
    gemm_kernel<2><<<4096, 256, 0, stream>>>(cur2, prev2, mm, hist, list, lcnt, flag);
    fin_kernel<<<1, 64, 0, stream>>>(hist, W, flag, out);
  }
}

// Round 5
// 284.952 us; speedup vs baseline: 6.1098x; 1.5640x over previous
//
#include <hip/hip_runtime.h>

typedef __attribute__((ext_vector_type(8))) short short8v;   // 8 bf16 (4 VGPRs)
typedef __attribute__((ext_vector_type(4))) float f32x4;     // MFMA accumulator

#define N_ROWS 8192
#define KSPLIT 768          // 3 x 256 (hi|lo|hi concatenation)
#define SEP 64
#define TLO (-50.0f)
#define THI (50.0f)
#define LIST_CAP (1u << 20)
#define TAIL_CAP 2048u      // tail buffer overlaid on Bs (8192 B = 2048 floats)

// ---------- helpers ----------
__device__ inline unsigned f2ord(float x){
  unsigned u = __float_as_uint(x);
  return (u & 0x80000000u) ? ~u : (u | 0x80000000u);   // monotone f32 -> u32
}
__device__ inline float ord2f(unsigned u){
  unsigned b = (u & 0x80000000u) ? (u & 0x7fffffffu) : ~u;
  return __uint_as_float(b);
}
__device__ inline unsigned short bf16rn(float x){
  unsigned b = __float_as_uint(x);
  unsigned r = (b + 0x7fffu + ((b >> 16) & 1u)) >> 16;  // round-to-nearest-even
  return (unsigned short)r;
}
__device__ inline void gload16(const void* g, void* l){
  __builtin_amdgcn_global_load_lds((const __attribute__((address_space(1))) void*)g,
                                   (__attribute__((address_space(3))) void*)l, 16, 0, 0);
}
__device__ inline int bin_of(float v, float mnv, float interval){
  float r = (v - mnv) / interval;                       // true division, like ref
  int b = (int)floorf(r);
  return b < 0 ? 0 : (b > 63 ? 63 : b);
}

// ---------- K0: split f32 -> bf16 hi/lo, K-concatenated ----------
// cur2  = [hi | lo | hi]  (8192 x 768 bf16)
// prev2 = [hi | hi | lo]
// => sum over K=768 gives hi*hi + lo*hi + hi*lo (drops only lo*lo ~1e-4)
__global__ void split_kernel(const float* __restrict__ cur, const float* __restrict__ prev,
                             unsigned short* __restrict__ cur2, unsigned short* __restrict__ prev2){
  int g = blockIdx.x * blockDim.x + threadIdx.x;         // 0 .. 2*524288-1
  int isB = (g >= (N_ROWS * 256 / 4)) ? 1 : 0;
  int t = g - isB * (N_ROWS * 256 / 4);
  const float4 v = ((const float4*)(isB ? prev : cur))[t];
  int row = t >> 6;                                      // 64 float4 per 256-col row
  int col = (t & 63) << 2;
  float xs[4] = {v.x, v.y, v.z, v.w};
  unsigned short h[4], l[4];
  #pragma unroll
  for (int j = 0; j < 4; ++j){
    unsigned short hb = bf16rn(xs[j]);
    float hf = __uint_as_float(((unsigned)hb) << 16);
    h[j] = hb;
    l[j] = bf16rn(xs[j] - hf);                           // residual capture
  }
  unsigned short* dst = isB ? prev2 : cur2;
  size_t base = (size_t)row * KSPLIT + col;
  uint2 hw, lw;
  hw.x = (unsigned)h[0] | ((unsigned)h[1] << 16); hw.y = (unsigned)h[2] | ((unsigned)h[3] << 16);
  lw.x = (unsigned)l[0] | ((unsigned)l[1] << 16); lw.y = (unsigned)l[2] | ((unsigned)l[3] << 16);
  *(uint2*)(dst + base) = hw;
  if (!isB){
    *(uint2*)(dst + base + 256) = lw;
    *(uint2*)(dst + base + 512) = hw;
  } else {
    *(uint2*)(dst + base + 256) = hw;
    *(uint2*)(dst + base + 512) = lw;
  }
}

// ---------- GEMM: 128x128 tile, 4 waves (2x2), 16x16x32 bf16 MFMA ----------
// EPI 0: min/max only (fallback pass 1)
// EPI 2: exact 64-bin histogram (fallback pass 2; early-exits when *flag == 0)
// EPI 3: min/max + tail list (per-block aggregated; lbuf overlaid on Bs)
// LDS: only As+Bs declared (16384 B); all epilogue scratch overlays them,
// which is safe because the K-loop's trailing __syncthreads retires all
// LDS reads before the epilogue touches anything.
template<int EPI>
__global__ __launch_bounds__(256) void gemm_kernel(const unsigned short* __restrict__ A2,
                                                   const unsigned short* __restrict__ B2,
                                                   unsigned* __restrict__ mm,
                                                   unsigned* __restrict__ hist,
                                                   float* __restrict__ list,
                                                   unsigned* __restrict__ lcnt,
                                                   const unsigned* __restrict__ flag){
  if (EPI == 2){
    if (flag[0] == 0u) return;                           // main path succeeded: no-op
  }
  __shared__ unsigned short As[128 * 32];
  __shared__ unsigned short Bs[128 * 32];

  const int tid  = threadIdx.x;
  const int lane = tid & 63;
  const int wave = tid >> 6;
  const int bm = blockIdx.x >> 6;
  const int bn = blockIdx.x & 63;
  const int wr = wave >> 1, wc = wave & 1;

  const size_t aBase = (size_t)bm * 128 * KSPLIT;
  const size_t bBase = (size_t)bn * 128 * KSPLIT;
  const int id0 = tid, id1 = tid + 256;                  // 512 x 16B chunks per tile
  const size_t aOff0 = aBase + (size_t)(id0 >> 2) * KSPLIT + (id0 & 3) * 8;
  const size_t aOff1 = aBase + (size_t)(id1 >> 2) * KSPLIT + (id1 & 3) * 8;
  const size_t bOff0 = bBase + (size_t)(id0 >> 2) * KSPLIT + (id0 & 3) * 8;
  const size_t bOff1 = bBase + (size_t)(id1 >> 2) * KSPLIT + (id1 & 3) * 8;

  f32x4 acc[4][4];
  #pragma unroll
  for (int m = 0; m < 4; ++m)
    #pragma unroll
    for (int n = 0; n < 4; ++n)
      acc[m][n] = (f32x4){0.f, 0.f, 0.f, 0.f};

  const int rsel = lane & 15;
  const int ksel = (lane >> 4) * 8;

  for (int ks = 0; ks < KSPLIT / 32; ++ks){
    const int k0 = ks * 32;
    gload16(A2 + aOff0 + k0, As + id0 * 8);
    gload16(A2 + aOff1 + k0, As + id1 * 8);
    gload16(B2 + bOff0 + k0, Bs + id0 * 8);
    gload16(B2 + bOff1 + k0, Bs + id1 * 8);
    __syncthreads();
    short8v a[4], b[4];
    #pragma unroll
    for (int m = 0; m < 4; ++m)
      a[m] = *(const short8v*)(As + (wr * 64 + m * 16 + rsel) * 32 + ksel);
    #pragma unroll
    for (int n = 0; n < 4; ++n)
      b[n] = *(const short8v*)(Bs + (wc * 64 + n * 16 + rsel) * 32 + ksel);
    #pragma unroll
    for (int m = 0; m < 4; ++m)
      #pragma unroll
      for (int n = 0; n < 4; ++n)
        acc[m][n] = __builtin_amdgcn_mfma_f32_16x16x32_bf16(a[m], b[n], acc[m][n], 0, 0, 0);
    __syncthreads();
  }

  // ---- epilogue scratch overlays (As/Bs are dead now) ----
  float*    red  = (float*)As;                           // 8 floats   @ As[0..32)
  unsigned* lh   = (unsigned*)((char*)As + 64);          // 64 u32     @ As[64..320)
  unsigned* pcnt = (unsigned*)((char*)As + 512);         // [0]=count, [1]=base
  float*    lbuf = (float*)Bs;                           // 2048 floats

  if (EPI == 0 || EPI == 3){
    if (EPI == 3){
      if (tid == 0) pcnt[0] = 0u;
      __syncthreads();
    }
    float mn = 3.4e38f, mx = -3.4e38f;
    #pragma unroll
    for (int m = 0; m < 4; ++m)
      #pragma unroll
      for (int n = 0; n < 4; ++n)
        #pragma unroll
        for (int q = 0; q < 4; ++q){
          float v = acc[m][n][q];
          mn = fminf(mn, v); mx = fmaxf(mx, v);
          if (EPI == 3 && fabsf(v) > THI){               // tail: spill to LDS (rare)
            unsigned li = atomicAdd(&pcnt[0], 1u);
            if (li < TAIL_CAP) lbuf[li] = v;
            else {                                       // LDS overflow: direct global (rare^2)
              unsigned gi = atomicAdd(lcnt, 1u);
              if (gi < LIST_CAP) list[gi] = v;
            }
          }
        }
    #pragma unroll
    for (int off = 32; off; off >>= 1){
      mn = fminf(mn, __shfl_xor(mn, off));
      mx = fmaxf(mx, __shfl_xor(mx, off));
    }
    if (lane == 0){ red[wave] = mn; red[4 + wave] = mx; }
    __syncthreads();                                     // red + pcnt[0] final
    if (tid == 0){
      mn = fminf(fminf(red[0], red[1]), fminf(red[2], red[3]));
      mx = fmaxf(fmaxf(red[4], red[5]), fmaxf(red[6], red[7]));
      atomicMin(mm + 0, f2ord(mn));
      atomicMax(mm + 1, f2ord(mx));
      if (EPI == 3){
        unsigned c = pcnt[0];
        unsigned cc = c > TAIL_CAP ? TAIL_CAP : c;
        pcnt[1] = cc ? atomicAdd(lcnt, cc) : 0u;         // ONE global atomic per block
        pcnt[0] = cc;
      }
    }
    if (EPI == 3){
      __syncthreads();
      const unsigned cc = pcnt[0], base = pcnt[1];
      for (unsigned i = tid; i < cc; i += 256u){
        unsigned gi = base + i;
        if (gi < LIST_CAP) list[gi] = lbuf[i];
      }
    }
  }
  if (EPI == 2){
    if (tid < SEP) lh[tid] = 0u;
    __syncthreads();
    const float mnv = ord2f(mm[0]);
    const float mxv = ord2f(mm[1]);
    const float interval = (mxv - mnv) / 64.0f;
    #pragma unroll
    for (int m = 0; m < 4; ++m)
      #pragma unroll
      for (int n = 0; n < 4; ++n)
        #pragma unroll
        for (int q = 0; q < 4; ++q)
          atomicAdd(&lh[bin_of(acc[m][n][q], mnv, interval)], 1u);
    __syncthreads();
    if (tid < SEP){ unsigned c = lh[tid]; if (c) atomicAdd(hist + tid, c); }
  }
}

// ---------- tail histogram, multi-block (spreads the same-bin atomic load) ----------
__global__ __launch_bounds__(256) void hist_tail_kernel(const float* __restrict__ list,
                                                        const unsigned* __restrict__ lcnt,
                                                        const unsigned* __restrict__ mm,
                                                        unsigned* __restrict__ histT){
  __shared__ unsigned lh[SEP];
  const int tid = threadIdx.x;
  if (tid < SEP) lh[tid] = 0u;
  __syncthreads();
  const float mnv = ord2f(mm[0]);
  const float mxv = ord2f(mm[1]);
  const float interval = (mxv - mnv) / 64.0f;
  unsigned cnt = lcnt[0];
  const unsigned n = cnt > LIST_CAP ? LIST_CAP : cnt;
  const unsigned stride = gridDim.x * 256u;
  for (unsigned i = blockIdx.x * 256u + tid; i < n; i += stride)
    atomicAdd(&lh[bin_of(list[i], mnv, interval)], 1u);  // ~466/block: serialization trivial
  __syncthreads();
  if (tid < SEP){ unsigned c = lh[tid]; if (c) atomicAdd(histT + tid, c); }
}

// ---------- finalize from tail histogram (1 wave). flag: 0 = done, 1 = fallback ----
__global__ void finalize2_kernel(const unsigned* __restrict__ mm,
                                 const unsigned* __restrict__ lcnt,
                                 const unsigned* __restrict__ histT,
                                 const float* __restrict__ W,
                                 unsigned* __restrict__ flag,
                                 float* __restrict__ out){
  const int j = threadIdx.x;                             // 64 threads = 1 wave
  const float mnv = ord2f(mm[0]);
  const float mxv = ord2f(mm[1]);
  const float interval = (mxv - mnv) / 64.0f;
  const unsigned cnt = lcnt[0];
  // binning is monotone in v (f32 sub/div/floor preserve order), so:
  //  - every v with bin(v) < bin(TLO) satisfies v < TLO -> fully in list -> exact
  //  - every v with bin(v) > bin(THI) satisfies v > THI -> fully in list -> exact
  const int bLO = bin_of(TLO, mnv, interval);
  const int bHI = bin_of(THI, mnv, interval);
  bool ok = (cnt <= LIST_CAP) && (bLO >= 3) && (bHI <= 60) && (bLO < bHI)
            && (histT[bLO - 1] >= 30u) && (histT[bHI + 1] >= 30u);
  if (!ok) return;                                       // flag stays 1 -> exact fallback
  float beta;
  if (j < bLO || j > bHI) beta = 1.f / (1.f + expf(-(float)histT[j]));
  else beta = 1.0f;                                      // count >= 30 -> f32 sigmoid == 1.0f
  float p = beta * W[j];
  #pragma unroll
  for (int off = 32; off; off >>= 1) p += __shfl_down(p, off);
  if (j == 0){
    out[0] = 1.f / (1.f + expf(-p));
    flag[0] = 0u;
  }
}

// ---------- fallback finalize: out = sigmoid( sum_j sigmoid(count_j) * W_j ) ----------
__global__ void fin_kernel(const unsigned* __restrict__ hist, const float* __restrict__ W,
                           const unsigned* __restrict__ flag, float* __restrict__ out){
  if (flag[0] == 0u) return;                             // finalize2 already wrote out
  int j = threadIdx.x;                                   // 64 threads = 1 wave
  float beta = 1.f / (1.f + expf(-(float)hist[j]));
  float p = beta * W[j];
  #pragma unroll
  for (int off = 32; off; off >>= 1) p += __shfl_down(p, off);
  if (j == 0) out[0] = 1.f / (1.f + expf(-p));
}

extern "C" void kernel_launch(void* const* d_in, const int* in_sizes, int n_in,
                              void* d_out, int out_size, void* d_ws, size_t ws_size,
                              hipStream_t stream){
  const float* cur  = (const float*)d_in[0];
  const float* prev = (const float*)d_in[1];
  const float* W    = (const float*)d_in[2];
  float* out = (float*)d_out;
  char* ws = (char*)d_ws;

  // ws layout
  unsigned short* cur2  = (unsigned short*)ws;                 // 12,582,912 B
  unsigned short* prev2 = (unsigned short*)(ws + 12582912);    // 12,582,912 B
  unsigned* mm    = (unsigned*)(ws + 25165824);                // [min,max] ordered-u32
  unsigned* flag  = (unsigned*)(ws + 25165832);
  unsigned* lcnt  = (unsigned*)(ws + 25165836);
  unsigned* hist  = (unsigned*)(ws + 25165840);                // 64 x u32 (ends 25166096)
  unsigned* histT = (unsigned*)(ws + 25166096);                // 64 x u32 (ends 25166352)
  float*    list  = (float*)(ws + 25166592);                   // 4 MiB tail list
  const size_t NEED_NEW = 25166592 + (size_t)LIST_CAP * 4;     // ~29.4 MB

  // init: min <- +inf-order; {max, flag, lcnt, hist, histT} <- 0; then flag <- 1
  hipMemsetAsync(mm, 0xFF, 4, stream);
  hipMemsetAsync((char*)mm + 4, 0, 4 + 4 + 4 + 256 + 16 + 256, stream);
  hipMemsetAsync(flag, 1, 1, stream);                          // flag = 1 (fallback default)

  split_kernel<<<4096, 256, 0, stream>>>(cur, prev, cur2, prev2);

  if (ws_size >= NEED_NEW){
    // single-GEMM path: minmax + tail list, then parallel tail hist + analytic finalize
    gemm_kernel<3><<<4096, 256, 0, stream>>>(cur2, prev2, mm, hist, list, lcnt, flag);
    hist_tail_kernel<<<256, 256, 0, stream>>>(list, lcnt, mm, histT);
    finalize2_kernel<<<1, 64, 0, stream>>>(mm, lcnt, histT, W, flag, out);
    gemm_kernel<2><<<4096, 256, 0, stream>>>(cur2, prev2, mm, hist, list, lcnt, flag);
    fin_kernel<<<1, 64, 0, stream>>>(hist, W, flag, out);
  } else {
    // verified 2-pass path (flag stays 1 -> EPI2 + fin run fully)
    gemm_kernel<0><<<4096, 256, 0, stream>>>(cur2, prev2, mm, hist, list, lcnt, flag);
    gemm_kernel<2><<<4096, 256, 0, stream>>>(cur2, prev2, mm, hist, list, lcnt, flag);
    fin_kernel<<<1, 64, 0, stream>>>(hist, W, flag, out);
  }
}

// Round 6
// 176.907 us; speedup vs baseline: 9.8413x; 1.6107x over previous
//
#include <hip/hip_runtime.h>

typedef __attribute__((ext_vector_type(8))) short short8v;   // 8 bf16 (4 VGPRs)
typedef __attribute__((ext_vector_type(4))) float f32x4;     // MFMA accumulator

#define N_ROWS 8192
#define KSPLIT 768          // 3 x 256 (hi|lo|hi concatenation)
#define SEP 64
#define TDET 65.0f          // candidate-detection threshold on hi-only GEMM value
#define TEXACT 73.0f        // exact-bin boundary = TDET + guarded err bound (7.75) rounded up
#define VTOL 5.5f           // |v_exact - dequant(v_hi)| guard (3.25 model err + 2.25 quant)
#define LIST_CAP 524288u

// ---------- helpers ----------
__device__ inline unsigned f2ord(float x){
  unsigned u = __float_as_uint(x);
  return (u & 0x80000000u) ? ~u : (u | 0x80000000u);   // monotone f32 -> u32
}
__device__ inline float ord2f(unsigned u){
  unsigned b = (u & 0x80000000u) ? (u & 0x7fffffffu) : ~u;
  return __uint_as_float(b);
}
__device__ inline unsigned short bf16rn(float x){
  unsigned b = __float_as_uint(x);
  unsigned r = (b + 0x7fffu + ((b >> 16) & 1u)) >> 16;  // round-to-nearest-even
  return (unsigned short)r;
}
__device__ inline void gload16(const void* g, void* l){
  __builtin_amdgcn_global_load_lds((const __attribute__((address_space(1))) void*)g,
                                   (__attribute__((address_space(3))) void*)l, 16, 0, 0);
}
__device__ inline int bin_of(float v, float mnv, float interval){
  float r = (v - mnv) / interval;                       // true division, like ref
  int b = (int)floorf(r);
  return b < 0 ? 0 : (b > 63 ? 63 : b);
}

// ---------- K0: split f32 -> bf16 hi/lo, K-concatenated; block 0 inits control ----------
// cur2  = [hi | lo | hi]  (8192 x 768 bf16);  prev2 = [hi | hi | lo]
// First 256 cols of each are the hi parts -> hi-only GEMM reads k<256 at stride 768.
__global__ void split_kernel(const float* __restrict__ cur, const float* __restrict__ prev,
                             unsigned short* __restrict__ cur2, unsigned short* __restrict__ prev2,
                             unsigned* __restrict__ ctl){
  if (blockIdx.x == 0){
    // ctl: [0]=min(ord) [1]=max(ord) [2]=flag [3]=lcnt [4]=viol [5..68]=hist [69..132]=histT
    if (threadIdx.x == 0){
      ctl[0] = 0xFFFFFFFFu; ctl[1] = 0u; ctl[2] = 1u; ctl[3] = 0u; ctl[4] = 0u;
    }
    if (threadIdx.x < 64){ ctl[5 + threadIdx.x] = 0u; ctl[69 + threadIdx.x] = 0u; }
  }
  int g = blockIdx.x * blockDim.x + threadIdx.x;         // 0 .. 2*524288-1
  int isB = (g >= (N_ROWS * 256 / 4)) ? 1 : 0;
  int t = g - isB * (N_ROWS * 256 / 4);
  const float4 v = ((const float4*)(isB ? prev : cur))[t];
  int row = t >> 6;                                      // 64 float4 per 256-col row
  int col = (t & 63) << 2;
  float xs[4] = {v.x, v.y, v.z, v.w};
  unsigned short h[4], l[4];
  #pragma unroll
  for (int j = 0; j < 4; ++j){
    unsigned short hb = bf16rn(xs[j]);
    float hf = __uint_as_float(((unsigned)hb) << 16);
    h[j] = hb;
    l[j] = bf16rn(xs[j] - hf);                           // residual capture
  }
  unsigned short* dst = isB ? prev2 : cur2;
  size_t base = (size_t)row * KSPLIT + col;
  uint2 hw, lw;
  hw.x = (unsigned)h[0] | ((unsigned)h[1] << 16); hw.y = (unsigned)h[2] | ((unsigned)h[3] << 16);
  lw.x = (unsigned)l[0] | ((unsigned)l[1] << 16); lw.y = (unsigned)l[2] | ((unsigned)l[3] << 16);
  *(uint2*)(dst + base) = hw;
  if (!isB){
    *(uint2*)(dst + base + 256) = lw;
    *(uint2*)(dst + base + 512) = hw;
  } else {
    *(uint2*)(dst + base + 256) = hw;
    *(uint2*)(dst + base + 512) = lw;
  }
}

// ---------- GEMM: 128x128 tile, 4 waves (2x2), 16x16x32 bf16 MFMA ----------
// EPI 0: min/max only             (fallback pass 1; runs only when flag!=0)
// EPI 2: exact 64-bin histogram   (fallback pass 2; runs only when flag!=0)
// EPI 4: candidate spill (|v|>TDET -> packed u32), no LDS / no barriers in epilogue
template<int EPI, int KSTEPS>
__global__ __launch_bounds__(256) void gemm_kernel(const unsigned short* __restrict__ A2,
                                                   const unsigned short* __restrict__ B2,
                                                   unsigned* __restrict__ mm,
                                                   unsigned* __restrict__ hist,
                                                   unsigned* __restrict__ idxq,
                                                   unsigned* __restrict__ lcnt,
                                                   const unsigned* __restrict__ flag){
  if (EPI == 0 || EPI == 2){
    if (flag[0] == 0u) return;                           // analytic path succeeded: no-op
  }
  __shared__ unsigned short As[128 * 32];
  __shared__ unsigned short Bs[128 * 32];

  const int tid  = threadIdx.x;
  const int lane = tid & 63;
  const int wave = tid >> 6;
  // XCD-aware bijective swizzle (4096 blocks = 8 XCDs x 512): neighbors share L2
  const int swz = ((blockIdx.x & 7) << 9) | (blockIdx.x >> 3);
  const int bm = swz >> 6;
  const int bn = swz & 63;
  const int wr = wave >> 1, wc = wave & 1;

  const size_t aBase = (size_t)bm * 128 * KSPLIT;
  const size_t bBase = (size_t)bn * 128 * KSPLIT;
  const int id0 = tid, id1 = tid + 256;                  // 512 x 16B chunks per tile
  const size_t aOff0 = aBase + (size_t)(id0 >> 2) * KSPLIT + (id0 & 3) * 8;
  const size_t aOff1 = aBase + (size_t)(id1 >> 2) * KSPLIT + (id1 & 3) * 8;
  const size_t bOff0 = bBase + (size_t)(id0 >> 2) * KSPLIT + (id0 & 3) * 8;
  const size_t bOff1 = bBase + (size_t)(id1 >> 2) * KSPLIT + (id1 & 3) * 8;

  f32x4 acc[4][4];
  #pragma unroll
  for (int m = 0; m < 4; ++m)
    #pragma unroll
    for (int n = 0; n < 4; ++n)
      acc[m][n] = (f32x4){0.f, 0.f, 0.f, 0.f};

  const int rsel = lane & 15;
  const int ksel = (lane >> 4) * 8;

  for (int ks = 0; ks < KSTEPS; ++ks){
    const int k0 = ks * 32;
    gload16(A2 + aOff0 + k0, As + id0 * 8);
    gload16(A2 + aOff1 + k0, As + id1 * 8);
    gload16(B2 + bOff0 + k0, Bs + id0 * 8);
    gload16(B2 + bOff1 + k0, Bs + id1 * 8);
    __syncthreads();
    short8v a[4], b[4];
    #pragma unroll
    for (int m = 0; m < 4; ++m)
      a[m] = *(const short8v*)(As + (wr * 64 + m * 16 + rsel) * 32 + ksel);
    #pragma unroll
    for (int n = 0; n < 4; ++n)
      b[n] = *(const short8v*)(Bs + (wc * 64 + n * 16 + rsel) * 32 + ksel);
    #pragma unroll
    for (int m = 0; m < 4; ++m)
      #pragma unroll
      for (int n = 0; n < 4; ++n)
        acc[m][n] = __builtin_amdgcn_mfma_f32_16x16x32_bf16(a[m], b[n], acc[m][n], 0, 0, 0);
    __syncthreads();
  }

  // epilogue scratch overlays (As/Bs dead after last barrier)
  float*    red = (float*)As;                            // 8 floats
  unsigned* lh  = (unsigned*)((char*)As + 64);           // 64 u32

  if (EPI == 0){
    float mn = 3.4e38f, mx = -3.4e38f;
    #pragma unroll
    for (int m = 0; m < 4; ++m)
      #pragma unroll
      for (int n = 0; n < 4; ++n)
        #pragma unroll
        for (int q = 0; q < 4; ++q){
          float v = acc[m][n][q];
          mn = fminf(mn, v); mx = fmaxf(mx, v);
        }
    #pragma unroll
    for (int off = 32; off; off >>= 1){
      mn = fminf(mn, __shfl_xor(mn, off));
      mx = fmaxf(mx, __shfl_xor(mx, off));
    }
    if (lane == 0){ red[wave] = mn; red[4 + wave] = mx; }
    __syncthreads();
    if (tid == 0){
      mn = fminf(fminf(red[0], red[1]), fminf(red[2], red[3]));
      mx = fmaxf(fmaxf(red[4], red[5]), fmaxf(red[6], red[7]));
      atomicMin(mm + 0, f2ord(mn));
      atomicMax(mm + 1, f2ord(mx));
    }
  }
  if (EPI == 2){
    if (tid < SEP) lh[tid] = 0u;
    __syncthreads();
    const float mnv = ord2f(mm[0]);
    const float mxv = ord2f(mm[1]);
    const float interval = (mxv - mnv) / 64.0f;
    #pragma unroll
    for (int m = 0; m < 4; ++m)
      #pragma unroll
      for (int n = 0; n < 4; ++n)
        #pragma unroll
        for (int q = 0; q < 4; ++q)
          atomicAdd(&lh[bin_of(acc[m][n][q], mnv, interval)], 1u);
    __syncthreads();
    if (tid < SEP){ unsigned c = lh[tid]; if (c) atomicAdd(hist + tid, c); }
  }
  if (EPI == 4){
    // pass 1: per-lane tail mask over the 64 accumulator values
    unsigned long long mask = 0ull;
    #pragma unroll
    for (int m = 0; m < 4; ++m)
      #pragma unroll
      for (int n = 0; n < 4; ++n)
        #pragma unroll
        for (int q = 0; q < 4; ++q){
          int b = (m * 4 + n) * 4 + q;
          if (fabsf(acc[m][n][q]) > TDET) mask |= (1ull << b);
        }
    int cnt = __popcll(mask);
    int pre = cnt;                                       // inclusive prefix over 64 lanes
    #pragma unroll
    for (int off = 1; off < 64; off <<= 1){
      int t = __shfl_up(pre, off);
      if (lane >= off) pre += t;
    }
    int tot = __shfl(pre, 63);                           // wave total
    int base = 0;
    if (lane == 63 && tot > 0) base = (int)atomicAdd(lcnt, (unsigned)tot);
    base = __shfl(base, 63);                             // ONE global atomic per wave
    if (mask){
      unsigned kk = (unsigned)(base + pre - cnt);
      #pragma unroll
      for (int m = 0; m < 4; ++m)
        #pragma unroll
        for (int n = 0; n < 4; ++n)
          #pragma unroll
          for (int q = 0; q < 4; ++q){
            int b = (m * 4 + n) * 4 + q;
            if ((mask >> b) & 1ull){
              float v = acc[m][n][q];
              // D layout (m89/m91-verified): row=(lane>>4)*4+q, col=lane&15
              int i = bm * 128 + wr * 64 + m * 16 + ((lane >> 4) << 2) + q;
              int j = bn * 128 + wc * 64 + n * 16 + (lane & 15);
              int e = (int)((v + 144.0f) * (1.0f / 4.5f));  // 6-bit quant, step 4.5
              e = e < 0 ? 0 : (e > 63 ? 63 : e);
              if (kk < LIST_CAP)
                idxq[kk] = ((unsigned)e << 26) | ((unsigned)i << 13) | (unsigned)j;
              ++kk;
            }
          }
    }
  }
}

// ---------- exact f32 recompute of candidates (1 wave per candidate) ----------
__global__ __launch_bounds__(256) void recompute_kernel(const float* __restrict__ cur,
                                                        const float* __restrict__ prev,
                                                        const unsigned* __restrict__ idxq,
                                                        const unsigned* __restrict__ lcnt,
                                                        unsigned* __restrict__ mm,
                                                        unsigned* __restrict__ viol,
                                                        float* __restrict__ vex){
  const int lane = threadIdx.x & 63;
  const int w  = (blockIdx.x * blockDim.x + threadIdx.x) >> 6;
  const int nw = (gridDim.x * blockDim.x) >> 6;
  unsigned n = lcnt[0]; if (n > LIST_CAP) n = LIST_CAP;
  float wmn = 3.4e38f, wmx = -3.4e38f;
  bool any = false;
  for (unsigned c = w; c < n; c += (unsigned)nw){
    unsigned u = idxq[c];
    int i = (int)((u >> 13) & 8191u), j = (int)(u & 8191u);
    float4 a = ((const float4*)cur)[i * 64 + lane];      // wave reads 1KB contiguous (L2-hot)
    float4 b = ((const float4*)prev)[j * 64 + lane];
    float s = a.x * b.x + a.y * b.y + a.z * b.z + a.w * b.w;
    #pragma unroll
    for (int off = 32; off; off >>= 1) s += __shfl_xor(s, off);
    if (lane == 0){
      vex[c] = s;
      float dq = ((float)(u >> 26) + 0.5f) * 4.5f - 144.0f;
      if (fabsf(s - dq) > VTOL) atomicAdd(viol, 1u);     // layout/index guard
    }
    wmn = fminf(wmn, s); wmx = fmaxf(wmx, s);
    any = true;
  }
  if (lane == 0 && any){
    atomicMin(mm + 0, f2ord(wmn));
    atomicMax(mm + 1, f2ord(wmx));
  }
}

// ---------- histogram of exact candidate values ----------
__global__ __launch_bounds__(256) void hist_tail_kernel(const float* __restrict__ vex,
                                                        const unsigned* __restrict__ lcnt,
                                                        const unsigned* __restrict__ mm,
                                                        unsigned* __restrict__ histT){
  __shared__ unsigned lh[SEP];
  const int tid = threadIdx.x;
  if (tid < SEP) lh[tid] = 0u;
  __syncthreads();
  const float mnv = ord2f(mm[0]);
  const float mxv = ord2f(mm[1]);
  const float interval = (mxv - mnv) / 64.0f;
  unsigned cnt = lcnt[0];
  const unsigned n = cnt > LIST_CAP ? LIST_CAP : cnt;
  const unsigned stride = gridDim.x * 256u;
  for (unsigned i = blockIdx.x * 256u + tid; i < n; i += stride)
    atomicAdd(&lh[bin_of(vex[i], mnv, interval)], 1u);
  __syncthreads();
  if (tid < SEP){ unsigned c = lh[tid]; if (c) atomicAdd(histT + tid, c); }
}

// ---------- analytic finalize (1 wave). flag: 0 = done, 1 = exact fallback ----------
__global__ void finalize2_kernel(const unsigned* __restrict__ mm,
                                 const unsigned* __restrict__ lcnt,
                                 const unsigned* __restrict__ viol,
                                 const unsigned* __restrict__ histT,
                                 const float* __restrict__ W,
                                 unsigned* __restrict__ flag,
                                 float* __restrict__ out){
  const int j = threadIdx.x;                             // 64 threads = 1 wave
  const float mnv = ord2f(mm[0]);
  const float mxv = ord2f(mm[1]);
  const float interval = (mxv - mnv) / 64.0f;
  const unsigned cnt = lcnt[0];
  // Monotone binning: bin(v) < bin(-TEXACT) => v < -TEXACT => |v_hi| > TDET => candidate.
  // So bins j < bLO and j > bHI contain ONLY candidates -> histT counts are exact there.
  const int bLO = bin_of(-TEXACT, mnv, interval);
  const int bHI = bin_of( TEXACT, mnv, interval);
  bool ok = (cnt <= LIST_CAP) && (viol[0] == 0u) && (bLO >= 3) && (bHI <= 60) && (bLO < bHI)
            && (histT[bLO - 1] >= 30u) && (histT[bHI + 1] >= 30u);
  if (!ok) return;                                       // flag stays 1 -> exact fallback
  float beta;
  if (j < bLO || j > bHI) beta = 1.f / (1.f + expf(-(float)histT[j]));
  else beta = 1.0f;                                      // count >= 17 -> f32 sigmoid == 1.0f
  float p = beta * W[j];
  #pragma unroll
  for (int off = 32; off; off >>= 1) p += __shfl_down(p, off);
  if (j == 0){
    out[0] = 1.f / (1.f + expf(-p));
    flag[0] = 0u;
  }
}

// ---------- fallback finalize: out = sigmoid( sum_j sigmoid(count_j) * W_j ) ----------
__global__ void fin_kernel(const unsigned* __restrict__ hist, const float* __restrict__ W,
                           const unsigned* __restrict__ flag, float* __restrict__ out){
  if (flag[0] == 0u) return;                             // finalize2 already wrote out
  int j = threadIdx.x;                                   // 64 threads = 1 wave
  float beta = 1.f / (1.f + expf(-(float)hist[j]));
  float p = beta * W[j];
  #pragma unroll
  for (int off = 32; off; off >>= 1) p += __shfl_down(p, off);
  if (j == 0) out[0] = 1.f / (1.f + expf(-p));
}

extern "C" void kernel_launch(void* const* d_in, const int* in_sizes, int n_in,
                              void* d_out, int out_size, void* d_ws, size_t ws_size,
                              hipStream_t stream){
  const float* cur  = (const float*)d_in[0];
  const float* prev = (const float*)d_in[1];
  const float* W    = (const float*)d_in[2];
  float* out = (float*)d_out;
  char* ws = (char*)d_ws;

  // ws layout
  unsigned short* cur2  = (unsigned short*)ws;                 // 12,582,912 B
  unsigned short* prev2 = (unsigned short*)(ws + 12582912);    // 12,582,912 B -> 25,165,824
  unsigned* ctl   = (unsigned*)(ws + 25165824);                // control block (532 B, pad 768)
  unsigned* mm    = ctl + 0;                                   // [min,max] ordered-u32
  unsigned* flag  = ctl + 2;
  unsigned* lcnt  = ctl + 3;
  unsigned* viol  = ctl + 4;
  unsigned* hist  = ctl + 5;                                   // 64 x u32 (fallback)
  unsigned* histT = ctl + 69;                                  // 64 x u32 (analytic)
  unsigned* idxq  = (unsigned*)(ws + 25166592);                // 2 MiB packed candidates
  float*    vex   = (float*)(ws + 27263744);                   // 2 MiB exact values
  const size_t NEED_NEW = 29360896;                            // same as round-5 (known to fit)

  split_kernel<<<4096, 256, 0, stream>>>(cur, prev, cur2, prev2, ctl);

  if (ws_size >= NEED_NEW){
    // hi-only GEMM (K=256) + candidate spill; exact recompute of ~3K tails; analytic finalize
    gemm_kernel<4, 8><<<4096, 256, 0, stream>>>(cur2, prev2, mm, hist, idxq, lcnt, flag);
    recompute_kernel<<<256, 256, 0, stream>>>(cur, prev, idxq, lcnt, mm, viol, vex);
    hist_tail_kernel<<<64, 256, 0, stream>>>(vex, lcnt, mm, histT);
    finalize2_kernel<<<1, 64, 0, stream>>>(mm, lcnt, viol, histT, W, flag, out);
    // guarded exact fallback (no-ops when flag == 0)
    gemm_kernel<0, 24><<<4096, 256, 0, stream>>>(cur2, prev2, mm, hist, idxq, lcnt, flag);
    gemm_kernel<2, 24><<<4096, 256, 0, stream>>>(cur2, prev2, mm, hist, idxq, lcnt, flag);
    fin_kernel<<<1, 64, 0, stream>>>(hist, W, flag, out);
  } else {
    // verified 2-pass exact path (flag stays 1 -> EPI0 + EPI2 + fin run fully)
    gemm_kernel<0, 24><<<4096, 256, 0, stream>>>(cur2, prev2, mm, hist, idxq, lcnt, flag);
    gemm_kernel<2, 24><<<4096, 256, 0, stream>>>(cur2, prev2, mm, hist, idxq, lcnt, flag);
    fin_kernel<<<1, 64, 0, stream>>>(hist, W, flag, out);
  }
}